// Round 1
// baseline (2538.453 us; speedup 1.0000x reference)
//
#include <hip/hip_runtime.h>

#define N_NODES 50000
#define N_EDGES 800000
#define KDIM 256
#define LDK 72            // 64 + 8 pad (bf16 elems): 144B row stride -> 2-way bank alias only

typedef __attribute__((ext_vector_type(8))) short short8;
typedef __attribute__((ext_vector_type(4))) float floatx4;

__device__ __forceinline__ unsigned short f2bf(float f) {
    union { float f; unsigned int u; } c; c.f = f;
    unsigned int u = c.u;
    return (unsigned short)((u + 0x7fffu + ((u >> 16) & 1u)) >> 16);
}

// ---------------- weight conversion f32 -> bf16 ----------------
__global__ void convert_weights(const float* __restrict__ Wa, const float* __restrict__ We,
                                unsigned short* __restrict__ Wa_bf, unsigned short* __restrict__ We_bf) {
    int i = blockIdx.x * blockDim.x + threadIdx.x;
    if (i < 128 * 256) Wa_bf[i] = f2bf(Wa[i]);
    if (i < 256 * 256) We_bf[i] = f2bf(We[i]);
}

// ---------------- segment-sum scatter (atomics) ----------------
// one thread per (edge, 4-float quad): 32 threads per edge
__global__ void scatter_mean_accum(const float* __restrict__ efeats, const int* __restrict__ dst,
                                   float* __restrict__ s, float* __restrict__ cnt) {
    int i = blockIdx.x * 256 + threadIdx.x;   // i in [0, E*32)
    int e = i >> 5, q = i & 31;
    int d = dst[e];
    float4 v = ((const float4*)efeats)[e * 32 + q];
    float* p = s + d * 128 + q * 4;
    atomicAdd(p + 0, v.x);
    atomicAdd(p + 1, v.y);
    atomicAdd(p + 2, v.z);
    atomicAdd(p + 3, v.w);
    if (q == 0) atomicAdd(cnt + d, 1.0f);
}

// ---------------- node GEMM: h = relu([nfeats | mean] @ Wa^T + b) ----------------
// 128 nodes x 128 outs per block, K=256 in 4 chunks of 64. 4 waves, each 64x64.
__launch_bounds__(256, 2)
__global__ void node_gemm(const float* __restrict__ nfeats, const float* __restrict__ s,
                          const float* __restrict__ cnt, const unsigned short* __restrict__ Wa_bf,
                          const float* __restrict__ bias, float* __restrict__ h_out,
                          unsigned short* __restrict__ h_bf) {
    __shared__ short Als[128 * LDK];
    __shared__ short Bls[128 * LDK];
    const int tid = threadIdx.x;
    const int lane = tid & 63, wave = tid >> 6;
    const int wm = (wave >> 1) * 64, wn = (wave & 1) * 64;
    const int row_base = blockIdx.x * 128;
    const int lm = lane & 15, lq = lane >> 4;

    floatx4 acc[4][4] = {};

    const int qa = (tid & 15) * 4;   // f32 quad col within chunk
    const int ra = tid >> 4;         // row 0..15
    const int c8 = (tid & 7) * 8;    // bf16 oct col within chunk
    const int r8 = tid >> 3;         // row 0..31

    for (int kc = 0; kc < 4; ++kc) {
        // stage A: rows = nodes, cols = K chunk (convert f32 -> bf16)
        #pragma unroll
        for (int it = 0; it < 8; ++it) {
            int r = ra + it * 16;
            int node = row_base + r;
            if (node >= N_NODES) node = N_NODES - 1;
            float4 v;
            if (kc < 2) {
                v = *(const float4*)(nfeats + node * 128 + kc * 64 + qa);
            } else {
                v = *(const float4*)(s + node * 128 + (kc - 2) * 64 + qa);
                float inv = 1.0f / fmaxf(cnt[node], 1.0f);
                v.x *= inv; v.y *= inv; v.z *= inv; v.w *= inv;
            }
            short4 b4;
            b4.x = (short)f2bf(v.x); b4.y = (short)f2bf(v.y);
            b4.z = (short)f2bf(v.z); b4.w = (short)f2bf(v.w);
            *(short4*)&Als[r * LDK + qa] = b4;
        }
        // stage B: rows = output features n, cols = K chunk (already bf16)
        #pragma unroll
        for (int it = 0; it < 4; ++it) {
            int n = r8 + it * 32;
            short8 wv = *(const short8*)((const short*)Wa_bf + n * KDIM + kc * 64 + c8);
            *(short8*)&Bls[n * LDK + c8] = wv;
        }
        __syncthreads();
        #pragma unroll
        for (int ks = 0; ks < 2; ++ks) {
            int lk = ks * 32 + lq * 8;
            short8 af[4], bg[4];
            #pragma unroll
            for (int mi = 0; mi < 4; ++mi) af[mi] = *(short8*)&Als[(wm + mi * 16 + lm) * LDK + lk];
            #pragma unroll
            for (int ni = 0; ni < 4; ++ni) bg[ni] = *(short8*)&Bls[(wn + ni * 16 + lm) * LDK + lk];
            #pragma unroll
            for (int mi = 0; mi < 4; ++mi)
                #pragma unroll
                for (int ni = 0; ni < 4; ++ni)
                    acc[mi][ni] = __builtin_amdgcn_mfma_f32_16x16x32_bf16(af[mi], bg[ni], acc[mi][ni], 0, 0, 0);
        }
        __syncthreads();
    }

    // epilogue: +bias, relu, write f32 + bf16
    #pragma unroll
    for (int mi = 0; mi < 4; ++mi) {
        #pragma unroll
        for (int ni = 0; ni < 4; ++ni) {
            int n = wn + ni * 16 + lm;
            float b = bias[n];
            #pragma unroll
            for (int r = 0; r < 4; ++r) {
                int node = row_base + wm + mi * 16 + lq * 4 + r;
                if (node < N_NODES) {
                    float v = acc[mi][ni][r] + b;
                    v = fmaxf(v, 0.0f);
                    h_out[node * 128 + n] = v;
                    h_bf[node * 128 + n] = f2bf(v);
                }
            }
        }
    }
}

// ---------------- edge GEMM: edge = [h[src] | h[dst]] @ We^T + b ----------------
// 128 edges x 128 outs per block (grid.y = 2 covers 256 outs), K=256 in 4 chunks.
__launch_bounds__(256, 2)
__global__ void edge_gemm(const unsigned short* __restrict__ h_bf,
                          const int* __restrict__ src, const int* __restrict__ dst,
                          const unsigned short* __restrict__ We_bf, const float* __restrict__ bias,
                          float* __restrict__ e_out) {
    __shared__ short Als[128 * LDK];
    __shared__ short Bls[128 * LDK];
    const int tid = threadIdx.x;
    const int lane = tid & 63, wave = tid >> 6;
    const int wm = (wave >> 1) * 64, wn = (wave & 1) * 64;
    const int erow = blockIdx.x * 128;
    const int ncol = blockIdx.y * 128;
    const int lm = lane & 15, lq = lane >> 4;

    floatx4 acc[4][4] = {};

    const int c8 = (tid & 7) * 8;
    const int r8 = tid >> 3;   // 0..31

    for (int kc = 0; kc < 4; ++kc) {
        const int* idxp = (kc < 2) ? src : dst;
        const int hoff = (kc & 1) * 64;
        // stage A: gather bf16 h rows
        #pragma unroll
        for (int it = 0; it < 4; ++it) {
            int r = r8 + it * 32;
            int node = idxp[erow + r];
            short8 v = *(const short8*)((const short*)h_bf + node * 128 + hoff + c8);
            *(short8*)&Als[r * LDK + c8] = v;
        }
        // stage B: W_edge rows (n-major, k-contiguous)
        #pragma unroll
        for (int it = 0; it < 4; ++it) {
            int n = r8 + it * 32;
            short8 wv = *(const short8*)((const short*)We_bf + (ncol + n) * KDIM + kc * 64 + c8);
            *(short8*)&Bls[n * LDK + c8] = wv;
        }
        __syncthreads();
        #pragma unroll
        for (int ks = 0; ks < 2; ++ks) {
            int lk = ks * 32 + lq * 8;
            short8 af[4], bg[4];
            #pragma unroll
            for (int mi = 0; mi < 4; ++mi) af[mi] = *(short8*)&Als[(wm + mi * 16 + lm) * LDK + lk];
            #pragma unroll
            for (int ni = 0; ni < 4; ++ni) bg[ni] = *(short8*)&Bls[(wn + ni * 16 + lm) * LDK + lk];
            #pragma unroll
            for (int mi = 0; mi < 4; ++mi)
                #pragma unroll
                for (int ni = 0; ni < 4; ++ni)
                    acc[mi][ni] = __builtin_amdgcn_mfma_f32_16x16x32_bf16(af[mi], bg[ni], acc[mi][ni], 0, 0, 0);
        }
        __syncthreads();
    }

    // epilogue: +bias, write f32
    #pragma unroll
    for (int mi = 0; mi < 4; ++mi) {
        #pragma unroll
        for (int ni = 0; ni < 4; ++ni) {
            int n = ncol + wn + ni * 16 + lm;
            float b = bias[n];
            #pragma unroll
            for (int r = 0; r < 4; ++r) {
                int e = erow + wm + mi * 16 + lq * 4 + r;
                e_out[e * 256 + n] = acc[mi][ni][r] + b;
            }
        }
    }
}

extern "C" void kernel_launch(void* const* d_in, const int* in_sizes, int n_in,
                              void* d_out, int out_size, void* d_ws, size_t ws_size,
                              hipStream_t stream) {
    const float* nfeats = (const float*)d_in[0];
    const float* efeats = (const float*)d_in[1];
    const int*   src    = (const int*)d_in[2];
    const int*   dst    = (const int*)d_in[3];
    const float* Wa     = (const float*)d_in[4];
    const float* Wab    = (const float*)d_in[5];
    const float* We     = (const float*)d_in[6];
    const float* Web    = (const float*)d_in[7];

    float* h_out = (float*)d_out;                       // [N, 128]
    float* e_out = h_out + (size_t)N_NODES * 128;       // [E, 256]

    char* ws = (char*)d_ws;
    float* s            = (float*)ws;                            // 25,600,000 B
    float* cnt          = (float*)(ws + 25600000);               //    200,000 B
    unsigned short* hbf = (unsigned short*)(ws + 25800000);      // 12,800,000 B
    unsigned short* WaB = (unsigned short*)(ws + 38600000);      //     65,536 B
    unsigned short* WeB = (unsigned short*)(ws + 38665536);      //    131,072 B

    // zero segment-sum accumulators (ws is poisoned 0xAA before every launch)
    hipMemsetAsync(ws, 0, 25800000, stream);
    convert_weights<<<256, 256, 0, stream>>>(Wa, We, WaB, WeB);
    scatter_mean_accum<<<(N_EDGES * 32) / 256, 256, 0, stream>>>(efeats, dst, s, cnt);
    node_gemm<<<(N_NODES + 127) / 128, 256, 0, stream>>>(nfeats, s, cnt, WaB, Wab, h_out, hbf);
    edge_gemm<<<dim3(N_EDGES / 128, 2), 256, 0, stream>>>(hbf, src, dst, WeB, Web, e_out);
}